// Round 6
// baseline (583.196 us; speedup 1.0000x reference)
//
#include <hip/hip_runtime.h>
#include <cstdint>
#include <cstddef>

#define INP 2048
#define EMB 512
#define NHEAD 2
#define BSZ 16
#define SEQ 1024
#define LAMBDA 10.0f

typedef __attribute__((ext_vector_type(8))) short bf16x8;
typedef __attribute__((ext_vector_type(16))) float f32x16;

__device__ __forceinline__ short f2bf(float x) {
    union { float f; unsigned u; } v; v.f = x;
    unsigned r = v.u + 0x7fffu + ((v.u >> 16) & 1u);   // RTN-even
    return (short)(r >> 16);
}
__device__ __forceinline__ float bf2f(short h) {
    union { unsigned u; float f; } v; v.u = ((unsigned)(unsigned short)h) << 16;
    return v.f;
}
__device__ __forceinline__ void g2lds16(const void* g, void* l) {
    __builtin_amdgcn_global_load_lds(
        (const __attribute__((address_space(1))) unsigned int*)g,
        (__attribute__((address_space(3))) unsigned int*)l, 16, 0, 0);
}
// hi-word selector must be a literal constant -> template parameter
template <bool HI>
__device__ __forceinline__ int pk8(float a, float b, int old) {
    return __builtin_amdgcn_cvt_pk_fp8_f32(a, b, old, HI);
}
__device__ __forceinline__ void pack8f8(const float* v, unsigned* lo, unsigned* hi) {
    int l = pk8<false>(v[0], v[1], 0); l = pk8<true>(v[2], v[3], l);
    int h = pk8<false>(v[4], v[5], 0); h = pk8<true>(v[6], v[7], h);
    *lo = (unsigned)l; *hi = (unsigned)h;
}

#define VM2() asm volatile("s_waitcnt vmcnt(2)" ::: "memory")
#define VM0() asm volatile("s_waitcnt vmcnt(0)" ::: "memory")

#define MFMAS(AO, BO) do { \
    __builtin_amdgcn_s_setprio(1); \
    _Pragma("unroll") for (int ks_ = 0; ks_ < 2; ks_++) \
    _Pragma("unroll") for (int i_ = 0; i_ < 4; i_++) \
    _Pragma("unroll") for (int j_ = 0; j_ < 2; j_++) \
        acc[i_][j_] = __builtin_amdgcn_mfma_f32_32x32x16_fp8_fp8( \
            AO[i_][ks_], BO[j_][ks_], acc[i_][j_], 0, 0, 0); \
    __builtin_amdgcn_s_setprio(0); \
} while (0)

#define READF(AO, BO, sl) do { \
    const char* bA_ = &sL[(sl)][0]; \
    const char* bB_ = &sL[(sl)][8192]; \
    _Pragma("unroll") for (int ks_ = 0; ks_ < 2; ks_++) { \
        const int pl_ = (ks_ * 2 + khl) * 256; \
        _Pragma("unroll") for (int i_ = 0; i_ < 4; i_++) \
            AO[i_][ks_] = *(const long*)&bA_[(pl_ + wm + i_ * 32 + fm) * 8]; \
        _Pragma("unroll") for (int j_ = 0; j_ < 2; j_++) \
            BO[j_][ks_] = *(const long*)&bB_[(pl_ + wn + j_ * 32 + fm) * 8]; \
    } \
} while (0)

// ---------------------------------------------------------------------------
__global__ __launch_bounds__(256) void zero_kernel(float* __restrict__ p, int n) {
    int i = blockIdx.x * 256 + threadIdx.x;
    if (i < n) p[i] = 0.f;
}

// ---------------------------------------------------------------------------
// Transpose+convert to k-major 8B fp8 slots:
// src slab [INP][L] fp32 -> slot layout [kg=INP/8][L] (slot = 8 consecutive
// k as fp8 e4m3). Block: 32 d x 64 l tile. grid: (L/64, INP/32, slabs).
// ---------------------------------------------------------------------------
__global__ __launch_bounds__(256) void conv_t(const float* __restrict__ src,
                                              char* __restrict__ out, int L) {
    const int l0 = blockIdx.x * 64;
    const int d0 = blockIdx.y * 32;
    const float* s = src + (size_t)blockIdx.z * INP * L;

    __shared__ float tl[32][65];
    const int t  = threadIdx.x;
    const int dr = t >> 3;
    const int f4 = (t & 7) * 4;

    float4 v0 = *(const float4*)&s[(size_t)(d0 + dr) * L + l0 + f4];
    float4 v1 = *(const float4*)&s[(size_t)(d0 + dr) * L + l0 + f4 + 32];
    tl[dr][f4 + 0] = v0.x; tl[dr][f4 + 1] = v0.y; tl[dr][f4 + 2] = v0.z; tl[dr][f4 + 3] = v0.w;
    tl[dr][f4 + 32] = v1.x; tl[dr][f4 + 33] = v1.y; tl[dr][f4 + 34] = v1.z; tl[dr][f4 + 35] = v1.w;
    __syncthreads();

    const int kgl = t >> 6;     // 0..3 (wave-uniform)
    const int l   = t & 63;
    float v[8];
#pragma unroll
    for (int q = 0; q < 8; q++) v[q] = tl[kgl * 8 + q][l];
    uint2 w;
    pack8f8(v, &w.x, &w.y);

    const size_t slot = (size_t)blockIdx.z * (INP / 8) * L
                      + (size_t)(blockIdx.y * 4 + kgl) * L + l0 + l;
    *(uint2*)&out[slot * 8] = w;
}

// ---------------------------------------------------------------------------
// fp8 MFMA projection GEMM, ring-4 + register-double-buffer pipeline:
// 256x256 block tile, 8 waves (2M x 4N), wave 128x64, BK=32.
// ds_reads for tile t+1 issue BEFORE the barrier ending iter t (latency
// hidden under MFMA+sync); counted vmcnt(2) never drains in-loop.
// A = iT slab [256 kg][1024 l] fp8 slots, B = Wt [h][256 kg][512 e].
// grid 512 (XCD-swizzled), block 512.
// ---------------------------------------------------------------------------
__global__ __launch_bounds__(512, 2) void proj_gemm(
    const char* __restrict__ iT, const char* __restrict__ Wt,
    const float* __restrict__ bias, float* __restrict__ Q) {
    const int bid = blockIdx.x;
    const int xcd = bid & 7;
    const int s   = bid >> 3;          // 0..63
    const int g   = s >> 2;            // 0..15 per-XCD (slab,mtile) group
    const int v   = s & 3;             // A-panel reuse: 2 heads x 2 n-halves
    const int h   = v >> 1;
    const int nh  = v & 1;
    const int gg  = xcd * 16 + g;      // 0..127
    const int slab  = gg >> 2;         // 0..31
    const int mtile = gg & 3;          // 0..3
    const int mb = mtile * 256;
    const int nb = nh * 256;
    const int im = slab >> 4;
    const int b  = slab & 15;
    const int z  = (im * 2 + h) * 16 + b;

    const char* __restrict__ Ag = iT + (size_t)slab * INP * SEQ;
    const char* __restrict__ Bg = Wt + (size_t)h * INP * EMB;

    __shared__ char sL[4][16384];      // ring: [A 8KB][B 8KB] per slot, 64 KB

    const int tid  = threadIdx.x;
    const int lane = tid & 63;
    const int wid  = tid >> 6;
    const int wm   = (wid >> 2) * 128;
    const int wn   = (wid & 3) * 64;
    const int fm   = lane & 31;
    const int khl  = lane >> 5;

#define P_STAGE(tt) do { \
    const int k8_ = (tt) * 4 + (wid >> 1); \
    const int ro_ = (wid & 1) * 128 + lane * 2; \
    char* d_ = &sL[(tt) & 3][(wid >> 1) * 2048 + (wid & 1) * 1024 + lane * 16]; \
    g2lds16(Ag + ((size_t)k8_ * SEQ + mb + ro_) * 8, d_); \
    g2lds16(Bg + ((size_t)k8_ * EMB + nb + ro_) * 8, d_ + 8192); \
} while (0)

    float bj[2];
#pragma unroll
    for (int j = 0; j < 2; j++) bj[j] = bias[h * EMB + nb + wn + j * 32 + fm];
    VM0();   // drain bias so in-loop vmcnt counts are pure

    f32x16 acc[4][2];
#pragma unroll
    for (int i = 0; i < 4; i++)
#pragma unroll
        for (int j = 0; j < 2; j++)
#pragma unroll
            for (int r = 0; r < 16; r++) acc[i][j][r] = 0.f;

    long a0[4][2], b0[2][2], a1[4][2], b1[2][2];

    P_STAGE(0); P_STAGE(1); P_STAGE(2);
    VM2();                              // stages 0,1 landed
    __builtin_amdgcn_s_barrier();
    READF(a0, b0, 0);

    for (int t = 0; t < 64; t += 2) {
        // even: compute set0 (tile t), read set1 (tile t+1)
        if (t + 3 < 64) P_STAGE(t + 3);
        READF(a1, b1, (t + 1) & 3);
        MFMAS(a0, b0);
        if (t + 3 < 64) VM2();
        __builtin_amdgcn_s_barrier();
        // odd: compute set1 (tile t+1), read set0 (tile t+2)
        const int u = t + 1;
        if (u + 3 < 64) P_STAGE(u + 3);
        if (u + 1 < 64) READF(a0, b0, (u + 1) & 3);
        MFMAS(a1, b1);
        if (u + 3 < 64) VM2();
        else if (u == 61) VM0();        // drain stage 63 for tile-63 reads
        if (u + 1 < 64) __builtin_amdgcn_s_barrier();
    }
#undef P_STAGE

    // epilogue: bias + fp32 C write (norm is a separate pass)
    float* __restrict__ Qz = Q + (size_t)z * SEQ * EMB;
#pragma unroll
    for (int i = 0; i < 4; i++)
#pragma unroll
        for (int r = 0; r < 16; r++) {
            const int row = mb + wm + i * 32 + (r & 3) + 8 * (r >> 2) + khl * 4;
#pragma unroll
            for (int j = 0; j < 2; j++)
                Qz[(size_t)row * EMB + nb + wn + j * 32 + fm] = acc[i][j][r] + bj[j];
        }
}

// ---------------------------------------------------------------------------
// Row L2-norm of Q (fp32), fold LAMBDA into image-1 slabs, emit fp8 k-major
// slots [z][kg=EMB/8][SEQ]. Block: 4 rows (1 wave each).
// grid: (SEQ/4, 64), block 256
// ---------------------------------------------------------------------------
__global__ __launch_bounds__(256) void norm_split(const float* __restrict__ Q,
                                                  char* __restrict__ Qf8) {
    const int z  = blockIdx.y;
    const int r0 = blockIdx.x * 4;
    const int t  = threadIdx.x;
    const int w    = t >> 6;
    const int lane = t & 63;
    const float* p = Q + ((size_t)z * SEQ + r0 + w) * EMB;

    float4 a = *(const float4*)&p[lane * 8];
    float4 b = *(const float4*)&p[lane * 8 + 4];
    float sq = a.x * a.x + a.y * a.y + a.z * a.z + a.w * a.w
             + b.x * b.x + b.y * b.y + b.z * b.z + b.w * b.w;
#pragma unroll
    for (int o = 32; o > 0; o >>= 1) sq += __shfl_xor(sq, o);
    float scale = 1.f / fmaxf(sqrtf(sq), 1e-12f);
    if (z < NHEAD * BSZ) scale *= LAMBDA;

    float v[8] = {a.x * scale, a.y * scale, a.z * scale, a.w * scale,
                  b.x * scale, b.y * scale, b.z * scale, b.w * scale};
    uint2 o2;
    pack8f8(v, &o2.x, &o2.y);

    __shared__ unsigned sh[64 * 4 * 2];
    sh[(lane * 4 + w) * 2]     = o2.x;   // slot: kg=lane, row_local=w
    sh[(lane * 4 + w) * 2 + 1] = o2.y;
    __syncthreads();

    // thread t -> slot t: kg = t>>2, row_local = t&3; coalesced
    const int kg = t >> 2, rl = t & 3;
    const size_t dst = ((size_t)z * (EMB / 8) + kg) * SEQ + r0 + rl;
    uint2 w2; w2.x = sh[t * 2]; w2.y = sh[t * 2 + 1];
    *(uint2*)&Qf8[dst * 8] = w2;
}

// ---------------------------------------------------------------------------
// fp8 MFMA attention on the same ring-4 + reg-DB skeleton.
// 256x256 tile, 8 waves, N=16 K-steps over EMB=512. E bf16 row-major.
// grid 1024 (XCD-swizzled), block 512.
// ---------------------------------------------------------------------------
__global__ __launch_bounds__(512, 2) void attn_mfma(
    const char* __restrict__ Qf8,
    short* __restrict__ E, float* __restrict__ Zr, float* __restrict__ Zc) {
    const int bid = blockIdx.x;
    const int xcd = bid & 7;
    const int s   = bid >> 3;            // 0..127
    const int hb  = xcd * 8 + (s >> 4);  // 0..63
    const int t4  = s & 15;
    const int l0  = (t4 >> 2) * 256;
    const int m0  = (t4 & 3) * 256;

    const char* __restrict__ Ag = Qf8 + (size_t)hb * EMB * SEQ;
    const char* __restrict__ Bg = Qf8 + (size_t)(NHEAD * BSZ + hb) * EMB * SEQ;

    __shared__ char sL[4][16384];
    __shared__ float redR[256], redC[256];

    const int tid  = threadIdx.x;
    const int lane = tid & 63;
    const int wid  = tid >> 6;
    const int wm   = (wid >> 2) * 128;
    const int wn   = (wid & 3) * 64;
    const int fm   = lane & 31;
    const int khl  = lane >> 5;

#define A_STAGE(tt) do { \
    const int k8_ = (tt) * 4 + (wid >> 1); \
    const int ro_ = (wid & 1) * 128 + lane * 2; \
    char* d_ = &sL[(tt) & 3][(wid >> 1) * 2048 + (wid & 1) * 1024 + lane * 16]; \
    g2lds16(Ag + ((size_t)k8_ * SEQ + l0 + ro_) * 8, d_); \
    g2lds16(Bg + ((size_t)k8_ * SEQ + m0 + ro_) * 8, d_ + 8192); \
} while (0)

    f32x16 acc[4][2];
#pragma unroll
    for (int i = 0; i < 4; i++)
#pragma unroll
        for (int j = 0; j < 2; j++)
#pragma unroll
            for (int r = 0; r < 16; r++) acc[i][j][r] = 0.f;

    long a0[4][2], b0[2][2], a1[4][2], b1[2][2];

    A_STAGE(0); A_STAGE(1); A_STAGE(2);
    VM2();
    __builtin_amdgcn_s_barrier();
    READF(a0, b0, 0);

    for (int t = 0; t < 16; t += 2) {
        if (t + 3 < 16) A_STAGE(t + 3);
        READF(a1, b1, (t + 1) & 3);
        MFMAS(a0, b0);
        if (t + 3 < 16) VM2();
        __builtin_amdgcn_s_barrier();
        const int u = t + 1;
        if (u + 3 < 16) A_STAGE(u + 3);
        if (u + 1 < 16) READF(a0, b0, (u + 1) & 3);
        MFMAS(a1, b1);
        if (u + 3 < 16) VM2();
        else if (u == 13) VM0();
        if (u + 1 < 16) __builtin_amdgcn_s_barrier();
    }
#undef A_STAGE

    if (tid < 256) { redR[tid] = 0.f; redC[tid] = 0.f; }
    __syncthreads();

    short* __restrict__ Ez = E + (size_t)hb * SEQ * SEQ;
    float cj0 = 0.f, cj1 = 0.f;
#pragma unroll
    for (int i = 0; i < 4; i++) {
        float ci0 = 0.f, ci1 = 0.f;
#pragma unroll
        for (int r = 0; r < 16; r++) {
            const int row = wm + i * 32 + (r & 3) + 8 * (r >> 2) + khl * 4;
            const short e0s = f2bf(expf(acc[i][0][r]));
            const short e1s = f2bf(expf(acc[i][1][r]));
            const float e0v = bf2f(e0s);
            const float e1v = bf2f(e1s);
            Ez[(size_t)(l0 + row) * SEQ + m0 + wn + fm]      = e0s;
            Ez[(size_t)(l0 + row) * SEQ + m0 + wn + 32 + fm] = e1s;
            float rv = e0v + e1v;
#pragma unroll
            for (int o = 16; o > 0; o >>= 1) rv += __shfl_xor(rv, o);
            if ((lane & 31) == 0) atomicAdd(&redR[row], rv);
            ci0 += e0v; ci1 += e1v;
        }
        cj0 += ci0; cj1 += ci1;
    }
    cj0 += __shfl_xor(cj0, 32);
    cj1 += __shfl_xor(cj1, 32);
    if (lane < 32) {
        atomicAdd(&redC[wn + fm], cj0);
        atomicAdd(&redC[wn + 32 + fm], cj1);
    }
    __syncthreads();

    if (tid < 256) {
        atomicAdd(&Zr[hb * SEQ + l0 + tid], redR[tid]);
        atomicAdd(&Zc[hb * SEQ + m0 + tid], redC[tid]);
    }
}

// ---------------------------------------------------------------------------
// Pass 2 (memory-bound, bf16 E):
// S21[l] = sum_m E[l][m]/Zc[m]; S12[m] = sum_l E[l][m]/Zr[l]
// ---------------------------------------------------------------------------
__global__ __launch_bounds__(256) void reduce_pass(
    const short* __restrict__ E, const float* __restrict__ Zr,
    const float* __restrict__ Zc, float* __restrict__ S21, float* __restrict__ S12) {
    const int lblk = blockIdx.x;
    const int hb   = blockIdx.y;
    const int tid  = threadIdx.x;
    const int lane = tid & 63;
    const int wid  = tid >> 6;
    const short* __restrict__ Ez = E + (size_t)hb * SEQ * SEQ;

    __shared__ float colred[SEQ];
    for (int i = tid; i < SEQ; i += 256) colred[i] = 0.f;
    __syncthreads();

    float izc[2][8];
#pragma unroll
    for (int it = 0; it < 2; it++)
#pragma unroll
        for (int q = 0; q < 8; q++)
            izc[it][q] = 1.f / Zc[hb * SEQ + it * 512 + lane * 8 + q];

    float colacc[2][8];
#pragma unroll
    for (int it = 0; it < 2; it++)
#pragma unroll
        for (int q = 0; q < 8; q++) colacc[it][q] = 0.f;

    for (int rr = 0; rr < 32; rr++) {
        const int row = lblk * 128 + wid * 32 + rr;
        const float izr = 1.f / Zr[hb * SEQ + row];
        float rowsum = 0.f;
#pragma unroll
        for (int it = 0; it < 2; it++) {
            bf16x8 ev = *(const bf16x8*)&Ez[(size_t)row * SEQ + it * 512 + lane * 8];
#pragma unroll
            for (int q = 0; q < 8; q++) {
                const float e = bf2f(ev[q]);
                rowsum += e * izc[it][q];
                colacc[it][q] += e * izr;
            }
        }
#pragma unroll
        for (int o = 32; o > 0; o >>= 1) rowsum += __shfl_down(rowsum, o);
        if (lane == 0) S21[hb * SEQ + row] = rowsum;
    }
#pragma unroll
    for (int it = 0; it < 2; it++)
#pragma unroll
        for (int q = 0; q < 8; q++)
            atomicAdd(&colred[it * 512 + lane * 8 + q], colacc[it][q]);
    __syncthreads();
    for (int i = tid; i < SEQ; i += 256) atomicAdd(&S12[hb * SEQ + i], colred[i]);
}

// ---------------------------------------------------------------------------
__global__ __launch_bounds__(256) void fin_kernel(
    const float* __restrict__ S21, const float* __restrict__ S12,
    float* __restrict__ out) {
    const int z  = blockIdx.x;
    const int w  = z / (NHEAD * BSZ);
    const int hb = z % (NHEAD * BSZ);
    const float* __restrict__ src = (w == 0 ? S21 : S12) + (size_t)hb * SEQ;
    const int t = threadIdx.x;

    float s = 0.f;
    for (int i = t; i < SEQ; i += 256) s += src[i];
#pragma unroll
    for (int o = 32; o > 0; o >>= 1) s += __shfl_down(s, o);
    __shared__ float red[4];
    if ((t & 63) == 0) red[t >> 6] = s;
    __syncthreads();
    const float total = red[0] + red[1] + red[2] + red[3];
    const float inv = 1.f / (total + 1e-8f);
    for (int i = t; i < SEQ; i += 256)
        out[(size_t)z * SEQ + i] = src[i] * inv;
}

// ---------------------------------------------------------------------------
extern "C" void kernel_launch(void* const* d_in, const int* in_sizes, int n_in,
                              void* d_out, int out_size, void* d_ws, size_t ws_size,
                              hipStream_t stream) {
    const float* img1 = (const float*)d_in[0];
    const float* img2 = (const float*)d_in[1];
    const float* W    = (const float*)d_in[2];
    const float* bias = (const float*)d_in[3];
    float* out = (float*)d_out;

    const size_t QN  = (size_t)2 * NHEAD * BSZ * SEQ * EMB;  // 33,554,432 (fp8 bytes / fp32 count)
    const size_t WN  = (size_t)NHEAD * EMB * INP;            //  2,097,152 bytes
    const size_t CNF = (size_t)32 * SEQ * INP;               // 67,108,864 bytes

    char* Qf8 = (char*)d_ws;
    char* Wf8 = Qf8 + QN;
    char* iT8 = Wf8 + WN;
    float* Q  = (float*)(iT8 + CNF);   // QN floats; region reused as bf16 E
    short* E  = (short*)Q;
    float* Zr = Q + QN;
    float* Zc  = Zr + (size_t)NHEAD * BSZ * SEQ;
    float* S21 = Zc + (size_t)NHEAD * BSZ * SEQ;
    float* S12 = S21 + (size_t)NHEAD * BSZ * SEQ;

    zero_kernel<<<dim3(512), dim3(256), 0, stream>>>(Zr, 4 * NHEAD * BSZ * SEQ);

    // W[h][d][e] -> k-major fp8 Wt[h][kg][e]
    conv_t<<<dim3(EMB / 64, INP / 32, NHEAD), dim3(256), 0, stream>>>(W, Wf8, EMB);

    // img1 -> slabs 0..15, img2 -> slabs 16..31
    conv_t<<<dim3(SEQ / 64, INP / 32, 16), dim3(256), 0, stream>>>(img1, iT8, SEQ);
    conv_t<<<dim3(SEQ / 64, INP / 32, 16), dim3(256), 0, stream>>>(
        img2, iT8 + (size_t)16 * INP * SEQ, SEQ);

    proj_gemm<<<dim3(512), dim3(512), 0, stream>>>(iT8, Wf8, bias, Q);

    norm_split<<<dim3(SEQ / 4, 2 * NHEAD * BSZ), dim3(256), 0, stream>>>(Q, Qf8);

    attn_mfma<<<dim3(1024), dim3(512), 0, stream>>>(Qf8, E, Zr, Zc);

    reduce_pass<<<dim3(8, NHEAD * BSZ), dim3(256), 0, stream>>>(E, Zr, Zc, S21, S12);

    fin_kernel<<<dim3(2 * NHEAD * BSZ), dim3(256), 0, stream>>>(S21, S12, out);
    (void)in_sizes; (void)n_in; (void)out_size; (void)ws_size;
}

// Round 7
// 498.293 us; speedup vs baseline: 1.1704x; 1.1704x over previous
//
#include <hip/hip_runtime.h>
#include <cstdint>
#include <cstddef>

#define INP 2048
#define EMB 512
#define NHEAD 2
#define BSZ 16
#define SEQ 1024
#define LAMBDA 10.0f
#define LOG2E 1.4426950408889634f

typedef __attribute__((ext_vector_type(8))) short bf16x8;
typedef __attribute__((ext_vector_type(16))) float f32x16;

__device__ __forceinline__ short f2bf(float x) {
    union { float f; unsigned u; } v; v.f = x;
    unsigned r = v.u + 0x7fffu + ((v.u >> 16) & 1u);   // RTN-even
    return (short)(r >> 16);
}
__device__ __forceinline__ float bf2f(short h) {
    union { unsigned u; float f; } v; v.u = ((unsigned)(unsigned short)h) << 16;
    return v.f;
}
__device__ __forceinline__ void g2lds16(const void* g, void* l) {
    __builtin_amdgcn_global_load_lds(
        (const __attribute__((address_space(1))) unsigned int*)g,
        (__attribute__((address_space(3))) unsigned int*)l, 16, 0, 0);
}
// hi-word selector must be a literal constant -> template parameter
template <bool HI>
__device__ __forceinline__ int pk8(float a, float b, int old) {
    return __builtin_amdgcn_cvt_pk_fp8_f32(a, b, old, HI);
}
__device__ __forceinline__ void pack8f8(const float* v, unsigned* lo, unsigned* hi) {
    int l = pk8<false>(v[0], v[1], 0); l = pk8<true>(v[2], v[3], l);
    int h = pk8<false>(v[4], v[5], 0); h = pk8<true>(v[6], v[7], h);
    *lo = (unsigned)l; *hi = (unsigned)h;
}

#define VM2() asm volatile("s_waitcnt vmcnt(2)" ::: "memory")
#define VM0() asm volatile("s_waitcnt vmcnt(0)" ::: "memory")

#define MFMAS(AO, BO) do { \
    __builtin_amdgcn_s_setprio(1); \
    _Pragma("unroll") for (int ks_ = 0; ks_ < 2; ks_++) \
    _Pragma("unroll") for (int i_ = 0; i_ < 4; i_++) \
    _Pragma("unroll") for (int j_ = 0; j_ < 2; j_++) \
        acc[i_][j_] = __builtin_amdgcn_mfma_f32_32x32x16_fp8_fp8( \
            AO[i_][ks_], BO[j_][ks_], acc[i_][j_], 0, 0, 0); \
    __builtin_amdgcn_s_setprio(0); \
} while (0)

#define READF(AO, BO, sl) do { \
    const char* bA_ = &sL[(sl)][0]; \
    const char* bB_ = &sL[(sl)][8192]; \
    _Pragma("unroll") for (int ks_ = 0; ks_ < 2; ks_++) { \
        const int pl_ = (ks_ * 2 + khl) * 256; \
        _Pragma("unroll") for (int i_ = 0; i_ < 4; i_++) \
            AO[i_][ks_] = *(const long*)&bA_[(pl_ + wm + i_ * 32 + fm) * 8]; \
        _Pragma("unroll") for (int j_ = 0; j_ < 2; j_++) \
            BO[j_][ks_] = *(const long*)&bB_[(pl_ + wn + j_ * 32 + fm) * 8]; \
    } \
} while (0)

// ---------------------------------------------------------------------------
__global__ __launch_bounds__(256) void zero_kernel(float* __restrict__ p, int n) {
    int i = blockIdx.x * 256 + threadIdx.x;
    if (i < n) p[i] = 0.f;
}

// ---------------------------------------------------------------------------
// Transpose+convert to k-major 8B fp8 slots:
// src slab [INP][L] fp32 -> slot layout [kg=INP/8][L] (slot = 8 consecutive
// k as fp8 e4m3). Block: 32 d x 64 l tile. grid: (L/64, INP/32, slabs).
// ---------------------------------------------------------------------------
__global__ __launch_bounds__(256) void conv_t(const float* __restrict__ src,
                                              char* __restrict__ out, int L) {
    const int l0 = blockIdx.x * 64;
    const int d0 = blockIdx.y * 32;
    const float* s = src + (size_t)blockIdx.z * INP * L;

    __shared__ float tl[32][65];
    const int t  = threadIdx.x;
    const int dr = t >> 3;
    const int f4 = (t & 7) * 4;

    float4 v0 = *(const float4*)&s[(size_t)(d0 + dr) * L + l0 + f4];
    float4 v1 = *(const float4*)&s[(size_t)(d0 + dr) * L + l0 + f4 + 32];
    tl[dr][f4 + 0] = v0.x; tl[dr][f4 + 1] = v0.y; tl[dr][f4 + 2] = v0.z; tl[dr][f4 + 3] = v0.w;
    tl[dr][f4 + 32] = v1.x; tl[dr][f4 + 33] = v1.y; tl[dr][f4 + 34] = v1.z; tl[dr][f4 + 35] = v1.w;
    __syncthreads();

    const int kgl = t >> 6;     // 0..3 (wave-uniform)
    const int l   = t & 63;
    float v[8];
#pragma unroll
    for (int q = 0; q < 8; q++) v[q] = tl[kgl * 8 + q][l];
    uint2 w;
    pack8f8(v, &w.x, &w.y);

    const size_t slot = (size_t)blockIdx.z * (INP / 8) * L
                      + (size_t)(blockIdx.y * 4 + kgl) * L + l0 + l;
    *(uint2*)&out[slot * 8] = w;
}

// ---------------------------------------------------------------------------
// fp8 MFMA projection GEMM, ring-4 + register-double-buffer pipeline:
// 256x256 block tile, 8 waves (2M x 4N), wave 128x64, BK=32.
// C emitted as bf16 (norm pass reads bf16).
// grid 512 (XCD-swizzled), block 512.
// ---------------------------------------------------------------------------
__global__ __launch_bounds__(512, 2) void proj_gemm(
    const char* __restrict__ iT, const char* __restrict__ Wt,
    const float* __restrict__ bias, short* __restrict__ Qb) {
    const int bid = blockIdx.x;
    const int xcd = bid & 7;
    const int s   = bid >> 3;          // 0..63
    const int g   = s >> 2;            // 0..15 per-XCD (slab,mtile) group
    const int v   = s & 3;             // A-panel reuse: 2 heads x 2 n-halves
    const int h   = v >> 1;
    const int nh  = v & 1;
    const int gg  = xcd * 16 + g;      // 0..127
    const int slab  = gg >> 2;         // 0..31
    const int mtile = gg & 3;          // 0..3
    const int mb = mtile * 256;
    const int nb = nh * 256;
    const int im = slab >> 4;
    const int b  = slab & 15;
    const int z  = (im * 2 + h) * 16 + b;

    const char* __restrict__ Ag = iT + (size_t)slab * INP * SEQ;
    const char* __restrict__ Bg = Wt + (size_t)h * INP * EMB;

    __shared__ char sL[4][16384];      // ring: [A 8KB][B 8KB] per slot, 64 KB

    const int tid  = threadIdx.x;
    const int lane = tid & 63;
    const int wid  = tid >> 6;
    const int wm   = (wid >> 2) * 128;
    const int wn   = (wid & 3) * 64;
    const int fm   = lane & 31;
    const int khl  = lane >> 5;

#define P_STAGE(tt) do { \
    const int k8_ = (tt) * 4 + (wid >> 1); \
    const int ro_ = (wid & 1) * 128 + lane * 2; \
    char* d_ = &sL[(tt) & 3][(wid >> 1) * 2048 + (wid & 1) * 1024 + lane * 16]; \
    g2lds16(Ag + ((size_t)k8_ * SEQ + mb + ro_) * 8, d_); \
    g2lds16(Bg + ((size_t)k8_ * EMB + nb + ro_) * 8, d_ + 8192); \
} while (0)

    float bj[2];
#pragma unroll
    for (int j = 0; j < 2; j++) bj[j] = bias[h * EMB + nb + wn + j * 32 + fm];
    VM0();   // drain bias so in-loop vmcnt counts are pure

    f32x16 acc[4][2];
#pragma unroll
    for (int i = 0; i < 4; i++)
#pragma unroll
        for (int j = 0; j < 2; j++)
#pragma unroll
            for (int r = 0; r < 16; r++) acc[i][j][r] = 0.f;

    long a0[4][2], b0[2][2], a1[4][2], b1[2][2];

    P_STAGE(0); P_STAGE(1); P_STAGE(2);
    VM2();                              // stages 0,1 landed
    __builtin_amdgcn_s_barrier();
    READF(a0, b0, 0);

    for (int t = 0; t < 64; t += 2) {
        // even: compute set0 (tile t), read set1 (tile t+1)
        if (t + 3 < 64) P_STAGE(t + 3);
        READF(a1, b1, (t + 1) & 3);
        MFMAS(a0, b0);
        if (t + 3 < 64) VM2();
        __builtin_amdgcn_s_barrier();
        // odd: compute set1 (tile t+1), read set0 (tile t+2)
        const int u = t + 1;
        if (u + 3 < 64) P_STAGE(u + 3);
        if (u + 1 < 64) READF(a0, b0, (u + 1) & 3);
        MFMAS(a1, b1);
        if (u + 3 < 64) VM2();
        else if (u == 61) VM0();        // drain stage 63 for tile-63 reads
        if (u + 1 < 64) __builtin_amdgcn_s_barrier();
    }
#undef P_STAGE

    // epilogue: bias + bf16 C write (norm is a separate pass)
    short* __restrict__ Qz = Qb + (size_t)z * SEQ * EMB;
#pragma unroll
    for (int i = 0; i < 4; i++)
#pragma unroll
        for (int r = 0; r < 16; r++) {
            const int row = mb + wm + i * 32 + (r & 3) + 8 * (r >> 2) + khl * 4;
#pragma unroll
            for (int j = 0; j < 2; j++)
                Qz[(size_t)row * EMB + nb + wn + j * 32 + fm] = f2bf(acc[i][j][r] + bj[j]);
        }
}

// ---------------------------------------------------------------------------
// Row L2-norm of bf16 Q, fold LAMBDA into image-1 slabs, emit fp8 k-major
// slots [z][kg=EMB/8][SEQ]. Block: 4 rows (1 wave each).
// grid: (SEQ/4, 64), block 256
// ---------------------------------------------------------------------------
__global__ __launch_bounds__(256) void norm_split(const short* __restrict__ Qb,
                                                  char* __restrict__ Qf8) {
    const int z  = blockIdx.y;
    const int r0 = blockIdx.x * 4;
    const int t  = threadIdx.x;
    const int w    = t >> 6;
    const int lane = t & 63;
    const short* p = Qb + ((size_t)z * SEQ + r0 + w) * EMB;

    bf16x8 a8 = *(const bf16x8*)&p[lane * 8];
    float v[8];
#pragma unroll
    for (int q = 0; q < 8; q++) v[q] = bf2f(a8[q]);
    float sq = 0.f;
#pragma unroll
    for (int q = 0; q < 8; q++) sq += v[q] * v[q];
#pragma unroll
    for (int o = 32; o > 0; o >>= 1) sq += __shfl_xor(sq, o);
    float scale = 1.f / fmaxf(sqrtf(sq), 1e-12f);
    if (z < NHEAD * BSZ) scale *= LAMBDA;

#pragma unroll
    for (int q = 0; q < 8; q++) v[q] *= scale;
    uint2 o2;
    pack8f8(v, &o2.x, &o2.y);

    __shared__ unsigned sh[64 * 4 * 2];
    sh[(lane * 4 + w) * 2]     = o2.x;   // slot: kg=lane, row_local=w
    sh[(lane * 4 + w) * 2 + 1] = o2.y;
    __syncthreads();

    // thread t -> slot t: kg = t>>2, row_local = t&3; coalesced
    const int kg = t >> 2, rl = t & 3;
    const size_t dst = ((size_t)z * (EMB / 8) + kg) * SEQ + r0 + rl;
    uint2 w2; w2.x = sh[t * 2]; w2.y = sh[t * 2 + 1];
    *(uint2*)&Qf8[dst * 8] = w2;
}

// ---------------------------------------------------------------------------
// fp8 MFMA attention on the same ring-4 + reg-DB skeleton.
// 256x256 tile, 8 waves, N=16 K-steps over EMB=512. E bf16 row-major.
// grid 512 = 32 hb x 16 tiles (XCD-swizzled), block 512.
// ---------------------------------------------------------------------------
__global__ __launch_bounds__(512, 2) void attn_mfma(
    const char* __restrict__ Qf8,
    short* __restrict__ E, float* __restrict__ Zr, float* __restrict__ Zc) {
    const int bid = blockIdx.x;
    const int xcd = bid & 7;
    const int s   = bid >> 3;            // 0..63
    const int hb  = xcd * 4 + (s >> 4);  // 0..31 (bijective: 8 xcd x 4)
    const int t4  = s & 15;
    const int l0  = (t4 >> 2) * 256;
    const int m0  = (t4 & 3) * 256;

    const char* __restrict__ Ag = Qf8 + (size_t)hb * EMB * SEQ;
    const char* __restrict__ Bg = Qf8 + (size_t)(NHEAD * BSZ + hb) * EMB * SEQ;

    __shared__ char sL[4][16384];
    __shared__ float redR[256], redC[256];

    const int tid  = threadIdx.x;
    const int lane = tid & 63;
    const int wid  = tid >> 6;
    const int wm   = (wid >> 2) * 128;
    const int wn   = (wid & 3) * 64;
    const int fm   = lane & 31;
    const int khl  = lane >> 5;

#define A_STAGE(tt) do { \
    const int k8_ = (tt) * 4 + (wid >> 1); \
    const int ro_ = (wid & 1) * 128 + lane * 2; \
    char* d_ = &sL[(tt) & 3][(wid >> 1) * 2048 + (wid & 1) * 1024 + lane * 16]; \
    g2lds16(Ag + ((size_t)k8_ * SEQ + l0 + ro_) * 8, d_); \
    g2lds16(Bg + ((size_t)k8_ * SEQ + m0 + ro_) * 8, d_ + 8192); \
} while (0)

    f32x16 acc[4][2];
#pragma unroll
    for (int i = 0; i < 4; i++)
#pragma unroll
        for (int j = 0; j < 2; j++)
#pragma unroll
            for (int r = 0; r < 16; r++) acc[i][j][r] = 0.f;

    long a0[4][2], b0[2][2], a1[4][2], b1[2][2];

    A_STAGE(0); A_STAGE(1); A_STAGE(2);
    VM2();
    __builtin_amdgcn_s_barrier();
    READF(a0, b0, 0);

    for (int t = 0; t < 16; t += 2) {
        if (t + 3 < 16) A_STAGE(t + 3);
        READF(a1, b1, (t + 1) & 3);
        MFMAS(a0, b0);
        if (t + 3 < 16) VM2();
        __builtin_amdgcn_s_barrier();
        const int u = t + 1;
        if (u + 3 < 16) A_STAGE(u + 3);
        if (u + 1 < 16) READF(a0, b0, (u + 1) & 3);
        MFMAS(a1, b1);
        if (u + 3 < 16) VM2();
        else if (u == 13) VM0();
        if (u + 1 < 16) __builtin_amdgcn_s_barrier();
    }
#undef A_STAGE

    if (tid < 256) { redR[tid] = 0.f; redC[tid] = 0.f; }
    __syncthreads();

    short* __restrict__ Ez = E + (size_t)hb * SEQ * SEQ;
    float cj0 = 0.f, cj1 = 0.f;
#pragma unroll
    for (int i = 0; i < 4; i++) {
        float ci0 = 0.f, ci1 = 0.f;
#pragma unroll
        for (int r = 0; r < 16; r++) {
            const int row = wm + i * 32 + (r & 3) + 8 * (r >> 2) + khl * 4;
            const short e0s = f2bf(__builtin_amdgcn_exp2f(acc[i][0][r] * LOG2E));
            const short e1s = f2bf(__builtin_amdgcn_exp2f(acc[i][1][r] * LOG2E));
            const float e0v = bf2f(e0s);
            const float e1v = bf2f(e1s);
            Ez[(size_t)(l0 + row) * SEQ + m0 + wn + fm]      = e0s;
            Ez[(size_t)(l0 + row) * SEQ + m0 + wn + 32 + fm] = e1s;
            float rv = e0v + e1v;
#pragma unroll
            for (int o = 16; o > 0; o >>= 1) rv += __shfl_xor(rv, o);
            if ((lane & 31) == 0) atomicAdd(&redR[row], rv);
            ci0 += e0v; ci1 += e1v;
        }
        cj0 += ci0; cj1 += ci1;
    }
    cj0 += __shfl_xor(cj0, 32);
    cj1 += __shfl_xor(cj1, 32);
    if (lane < 32) {
        atomicAdd(&redC[wn + fm], cj0);
        atomicAdd(&redC[wn + 32 + fm], cj1);
    }
    __syncthreads();

    if (tid < 256) {
        atomicAdd(&Zr[hb * SEQ + l0 + tid], redR[tid]);
        atomicAdd(&Zc[hb * SEQ + m0 + tid], redC[tid]);
    }
}

// ---------------------------------------------------------------------------
// Pass 2 (memory-bound, bf16 E):
// S21[l] = sum_m E[l][m]/Zc[m]; S12[m] = sum_l E[l][m]/Zr[l]
// ---------------------------------------------------------------------------
__global__ __launch_bounds__(256) void reduce_pass(
    const short* __restrict__ E, const float* __restrict__ Zr,
    const float* __restrict__ Zc, float* __restrict__ S21, float* __restrict__ S12) {
    const int lblk = blockIdx.x;
    const int hb   = blockIdx.y;
    const int tid  = threadIdx.x;
    const int lane = tid & 63;
    const int wid  = tid >> 6;
    const short* __restrict__ Ez = E + (size_t)hb * SEQ * SEQ;

    __shared__ float colred[SEQ];
    for (int i = tid; i < SEQ; i += 256) colred[i] = 0.f;
    __syncthreads();

    float izc[2][8];
#pragma unroll
    for (int it = 0; it < 2; it++)
#pragma unroll
        for (int q = 0; q < 8; q++)
            izc[it][q] = 1.f / Zc[hb * SEQ + it * 512 + lane * 8 + q];

    float colacc[2][8];
#pragma unroll
    for (int it = 0; it < 2; it++)
#pragma unroll
        for (int q = 0; q < 8; q++) colacc[it][q] = 0.f;

    for (int rr = 0; rr < 32; rr++) {
        const int row = lblk * 128 + wid * 32 + rr;
        const float izr = 1.f / Zr[hb * SEQ + row];
        float rowsum = 0.f;
#pragma unroll
        for (int it = 0; it < 2; it++) {
            bf16x8 ev = *(const bf16x8*)&Ez[(size_t)row * SEQ + it * 512 + lane * 8];
#pragma unroll
            for (int q = 0; q < 8; q++) {
                const float e = bf2f(ev[q]);
                rowsum += e * izc[it][q];
                colacc[it][q] += e * izr;
            }
        }
#pragma unroll
        for (int o = 32; o > 0; o >>= 1) rowsum += __shfl_down(rowsum, o);
        if (lane == 0) S21[hb * SEQ + row] = rowsum;
    }
#pragma unroll
    for (int it = 0; it < 2; it++)
#pragma unroll
        for (int q = 0; q < 8; q++)
            atomicAdd(&colred[it * 512 + lane * 8 + q], colacc[it][q]);
    __syncthreads();
    for (int i = tid; i < SEQ; i += 256) atomicAdd(&S12[hb * SEQ + i], colred[i]);
}

// ---------------------------------------------------------------------------
__global__ __launch_bounds__(256) void fin_kernel(
    const float* __restrict__ S21, const float* __restrict__ S12,
    float* __restrict__ out) {
    const int z  = blockIdx.x;
    const int w  = z / (NHEAD * BSZ);
    const int hb = z % (NHEAD * BSZ);
    const float* __restrict__ src = (w == 0 ? S21 : S12) + (size_t)hb * SEQ;
    const int t = threadIdx.x;

    float s = 0.f;
    for (int i = t; i < SEQ; i += 256) s += src[i];
#pragma unroll
    for (int o = 32; o > 0; o >>= 1) s += __shfl_down(s, o);
    __shared__ float red[4];
    if ((t & 63) == 0) red[t >> 6] = s;
    __syncthreads();
    const float total = red[0] + red[1] + red[2] + red[3];
    const float inv = 1.f / (total + 1e-8f);
    for (int i = t; i < SEQ; i += 256)
        out[(size_t)z * SEQ + i] = src[i] * inv;
}

// ---------------------------------------------------------------------------
extern "C" void kernel_launch(void* const* d_in, const int* in_sizes, int n_in,
                              void* d_out, int out_size, void* d_ws, size_t ws_size,
                              hipStream_t stream) {
    const float* img1 = (const float*)d_in[0];
    const float* img2 = (const float*)d_in[1];
    const float* W    = (const float*)d_in[2];
    const float* bias = (const float*)d_in[3];
    float* out = (float*)d_out;

    const size_t QN  = (size_t)2 * NHEAD * BSZ * SEQ * EMB;  // 33,554,432
    const size_t WN  = (size_t)NHEAD * EMB * INP;            //  2,097,152 bytes
    const size_t CNF = (size_t)32 * SEQ * INP;               // 67,108,864 bytes

    char* Qf8 = (char*)d_ws;
    char* Wf8 = Qf8 + QN;
    char* iT8 = Wf8 + WN;
    short* Qb = (short*)(iT8 + CNF);   // QN bf16; region reused as bf16 E
    short* E  = Qb;
    float* Zr = (float*)(Qb + QN);
    float* Zc  = Zr + (size_t)NHEAD * BSZ * SEQ;
    float* S21 = Zc + (size_t)NHEAD * BSZ * SEQ;
    float* S12 = S21 + (size_t)NHEAD * BSZ * SEQ;

    zero_kernel<<<dim3(512), dim3(256), 0, stream>>>(Zr, 4 * NHEAD * BSZ * SEQ);

    // W[h][d][e] -> k-major fp8 Wt[h][kg][e]
    conv_t<<<dim3(EMB / 64, INP / 32, NHEAD), dim3(256), 0, stream>>>(W, Wf8, EMB);

    // img1 -> slabs 0..15, img2 -> slabs 16..31
    conv_t<<<dim3(SEQ / 64, INP / 32, 16), dim3(256), 0, stream>>>(img1, iT8, SEQ);
    conv_t<<<dim3(SEQ / 64, INP / 32, 16), dim3(256), 0, stream>>>(
        img2, iT8 + (size_t)16 * INP * SEQ, SEQ);

    proj_gemm<<<dim3(512), dim3(512), 0, stream>>>(iT8, Wf8, bias, Qb);

    norm_split<<<dim3(SEQ / 4, 2 * NHEAD * BSZ), dim3(256), 0, stream>>>(Qb, Qf8);

    attn_mfma<<<dim3(512), dim3(512), 0, stream>>>(Qf8, E, Zr, Zc);

    reduce_pass<<<dim3(8, NHEAD * BSZ), dim3(256), 0, stream>>>(E, Zr, Zc, S21, S12);

    fin_kernel<<<dim3(2 * NHEAD * BSZ), dim3(256), 0, stream>>>(S21, S12, out);
    (void)in_sizes; (void)n_in; (void)out_size; (void)ws_size;
}